// Round 6
// baseline (524.454 us; speedup 1.0000x reference)
//
#include <hip/hip_runtime.h>

typedef unsigned short u16;
typedef short bf16x8 __attribute__((ext_vector_type(8)));
typedef float floatx16 __attribute__((ext_vector_type(16)));

// ---------- bf16 helpers (bit-level RNE) --------------------------------------
static __device__ __forceinline__ u16 f2bf(float f) {
  unsigned int u = __float_as_uint(f);
  unsigned int lsb = (u >> 16) & 1u;
  u += 0x7FFFu + lsb;                 // round-to-nearest-even
  return (u16)(u >> 16);
}
static __device__ __forceinline__ float bf2f(u16 u) {
  return __uint_as_float(((unsigned int)u) << 16);
}

// ---------- async global->LDS, 16B per lane (dest = uniform base + lane*16) ----
static __device__ __forceinline__ void gl_lds16(const u16* g, u16* l) {
  __builtin_amdgcn_global_load_lds(
      (const __attribute__((address_space(1))) void*)g,
      (__attribute__((address_space(3))) void*)l, 16, 0, 0);
}

// ---------- weight prep: 4 transposes in one launch ----------------------------
// z=0: wq -> rows 0..1023 of qkvThi/qkvTlo; z=1: wk -> rows 1024..2047;
// z=2: wv -> rows 2048..3071 of qkvThi (hi only); z=3: wp -> wpThi (hi only)
__global__ __launch_bounds__(256)
void prep_weights(const float* __restrict__ wq, const float* __restrict__ wk,
                  const float* __restrict__ wv, const float* __restrict__ wp,
                  u16* __restrict__ qkvThi, u16* __restrict__ qkvTlo,
                  u16* __restrict__ wpThi) {
  __shared__ float t[32][33];
  const int z = blockIdx.z;
  const int tid = threadIdx.x;
  const float* in = (z == 0) ? wq : (z == 1) ? wk : (z == 2) ? wv : wp;
  u16* hi = (z == 3) ? wpThi : (qkvThi + (size_t)z * 1024 * 1024);
  u16* lo = (z == 0) ? qkvTlo : (z == 1) ? (qkvTlo + 1024 * 1024) : (u16*)nullptr;
  const int want_lo = (z < 2);

  const int r0 = blockIdx.y * 32, c0 = blockIdx.x * 32;
  const int lr = tid >> 3;            // 0..31
  const int lc = (tid & 7) * 4;       // 0,4,..,28
  float4 v = *(const float4*)(in + (size_t)(r0 + lr) * 1024 + c0 + lc);
  t[lr][lc + 0] = v.x; t[lr][lc + 1] = v.y; t[lr][lc + 2] = v.z; t[lr][lc + 3] = v.w;
  __syncthreads();
  u16 ph[4], pl[4];
#pragma unroll
  for (int j = 0; j < 4; j++) {
    float f = t[lc + j][lr];
    ph[j] = f2bf(f);
    pl[j] = f2bf(f - bf2f(ph[j]));
  }
  const size_t o = (size_t)(c0 + lr) * 1024 + r0 + lc;
  *(uint2*)(hi + o) = *(uint2*)ph;
  if (want_lo) *(uint2*)(lo + o) = *(uint2*)pl;
}

// ---------- fp32 [n] -> split-bf16 hi/lo (elementwise) -------------------------
__global__ __launch_bounds__(256)
void split_f32(const float* __restrict__ in, u16* __restrict__ hi,
               u16* __restrict__ lo) {
  const size_t i4 = ((size_t)blockIdx.x * 256 + threadIdx.x) * 4;
  float4 v = *(const float4*)(in + i4);
  float f[4] = {v.x, v.y, v.z, v.w};
  u16 ph[4], pl[4];
#pragma unroll
  for (int j = 0; j < 4; j++) {
    ph[j] = f2bf(f[j]);
    pl[j] = f2bf(f[j] - bf2f(ph[j]));
  }
  *(uint2*)(hi + i4) = *(uint2*)ph;
  *(uint2*)(lo + i4) = *(uint2*)pl;
}

// ---------- MFMA GEMM: C[M,N] = A[M,K] * B^T (B stored [N][K]) -----------------
// 128x128 tile / 256 threads; 4 waves, each 64x64 = 2x2 frags of 32x32x16 bf16
// (µbench 2382 TF vs 2075 for 16x16 — fewer, bigger MFMAs, same LDS traffic).
// KB = K-tile (32/64). Staging: global_load_lds 16B/lane into XOR-swizzled LDS
// (KB32: logical col-blk c of row r at phys c^((r>>1)&3); KB64: c^(r&7)) —
// DMA-legal AND exact 2-way (free) bank aliasing for the 32x32 frag b128 reads.
// ASP/BSP: hi/lo bf16 planes -> 3-term split product (hh + hl + lh).
// OM: 0 bf16 out, 1 split bf16 (hi->C0, lo->C1), 2 fp32 out,
//     3 bf16 transposed V-store vT[b][d][t], b=m>>11, t=m&2047 (2048x1024 hard).
template<int KB, int ASP, int BSP, int OM, int HB>
__global__ __launch_bounds__(256)
void gemm_mfma(const u16* __restrict__ Ahi, const u16* __restrict__ Alo,
               const u16* __restrict__ Bhi, const u16* __restrict__ Blo,
               const float* __restrict__ bias,
               void* __restrict__ C0, void* __restrict__ C1,
               int N, int K, int lda, int ldb, int ldc,
               long long aB, long long bB, long long cB, float scale) {
  constexpr int CM = KB / 8 - 1;      // col-block mask (3 or 7)
  constexpr int RPI = 512 / KB;       // rows per 1KB DMA issue (16 or 8)
  constexpr int NI = KB / 16;         // issues per wave per plane (2 or 4)
  constexpr int PL = 128 * KB;        // plane elems
  __shared__ __align__(16) u16 As[(1 + ASP) * PL];
  __shared__ __align__(16) u16 Bs[(1 + BSP) * PL];

  const int bz = blockIdx.z;
  const u16* A0 = Ahi + (size_t)bz * aB;
  const u16* A1 = ASP ? (Alo + (size_t)bz * aB) : (const u16*)nullptr;
  const u16* B0 = Bhi + (size_t)bz * bB;
  const u16* B1 = BSP ? (Blo + (size_t)bz * bB) : (const u16*)nullptr;

  const int m0 = blockIdx.y * 128;
  const int n0 = blockIdx.x * 128;
  const int tid = threadIdx.x;
  const int w = tid >> 6;
  const int L = tid & 63;
  const int l31 = L & 31, half = L >> 5;
  const int wm = (w >> 1) * 64, wn = (w & 1) * 64;

  // staging: wave w stages rows [w*32, w*32+32) of each 128xKB plane.
  const int lrow = (KB == 32) ? (L >> 2) : (L >> 3);
  const int c3 = (L & CM) ^ ((L >> 3) & CM);    // logical (global) col-block
  const int srow = w * 32 + lrow;
  u16* stA = &As[w * 32 * KB];
  u16* stB = &Bs[w * 32 * KB];
  const u16* gA0 = A0 + (size_t)(m0 + srow) * lda + c3 * 8;
  const u16* gA1 = ASP ? A1 + (size_t)(m0 + srow) * lda + c3 * 8 : (const u16*)nullptr;
  const u16* gB0 = B0 + (size_t)(n0 + srow) * ldb + c3 * 8;
  const u16* gB1 = BSP ? B1 + (size_t)(n0 + srow) * ldb + c3 * 8 : (const u16*)nullptr;

  floatx16 acc[2][2] = {};

  for (int k0 = 0; k0 < K; k0 += KB) {
#pragma unroll
    for (int q = 0; q < NI; q++) {
      gl_lds16(gA0 + k0 + (size_t)q * RPI * lda, stA + q * 512);
      gl_lds16(gB0 + k0 + (size_t)q * RPI * ldb, stB + q * 512);
    }
    if (ASP) {
#pragma unroll
      for (int q = 0; q < NI; q++)
        gl_lds16(gA1 + k0 + (size_t)q * RPI * lda, stA + PL + q * 512);
    }
    if (BSP) {
#pragma unroll
      for (int q = 0; q < NI; q++)
        gl_lds16(gB1 + k0 + (size_t)q * RPI * ldb, stB + PL + q * 512);
    }
    __syncthreads();                  // drains vmcnt(0) then barrier

#pragma unroll
    for (int s = 0; s < KB / 16; s++) {
      // A/B frag: lane holds row l31, k-chunk (s*16 + half*8 .. +8); phys
      // col-block via swizzle is lane-constant (wm/wn multiples of 32 vanish).
      const int pcb = ((KB == 32) ? ((s * 2 + half) ^ ((l31 >> 1) & 3))
                                  : ((s * 2 + half) ^ (l31 & 7))) * 8;
      bf16x8 a0[2], a1[2], b0[2], b1[2];
#pragma unroll
      for (int i = 0; i < 2; i++) {
        a0[i] = *(const bf16x8*)&As[(wm + i * 32 + l31) * KB + pcb];
        b0[i] = *(const bf16x8*)&Bs[(wn + i * 32 + l31) * KB + pcb];
        if (ASP) a1[i] = *(const bf16x8*)&As[PL + (wm + i * 32 + l31) * KB + pcb];
        if (BSP) b1[i] = *(const bf16x8*)&Bs[PL + (wn + i * 32 + l31) * KB + pcb];
      }
#pragma unroll
      for (int i = 0; i < 2; i++) {
#pragma unroll
        for (int j = 0; j < 2; j++) {
          acc[i][j] = __builtin_amdgcn_mfma_f32_32x32x16_bf16(a0[i], b0[j], acc[i][j], 0, 0, 0);
          if (ASP && BSP) {
            acc[i][j] = __builtin_amdgcn_mfma_f32_32x32x16_bf16(a0[i], b1[j], acc[i][j], 0, 0, 0);
            acc[i][j] = __builtin_amdgcn_mfma_f32_32x32x16_bf16(a1[i], b0[j], acc[i][j], 0, 0, 0);
          }
        }
      }
    }
    __syncthreads();                  // frag reads done before next DMA stage
  }

  // epilogue: 32x32 C/D (m74/m101-verified): col = l31, row = (r&3) + 8*(r>>2)
  // + 4*half, r = rq*4+ri.
#pragma unroll
  for (int i = 0; i < 2; i++) {
#pragma unroll
    for (int j = 0; j < 2; j++) {
      const int col = n0 + wn + j * 32 + l31;
      float bvs = 0.f;
      if (HB) bvs = bias[col];
#pragma unroll
      for (int rq = 0; rq < 4; rq++) {
        const int mb = m0 + wm + i * 32 + rq * 8 + half * 4;
        if (OM == 3) {
          u16 pk[4];
#pragma unroll
          for (int ri = 0; ri < 4; ri++)
            pk[ri] = f2bf(acc[i][j][rq * 4 + ri] * scale + bvs);
          const size_t idx = (size_t)(mb >> 11) * (2048 * 1024) +
                             (size_t)col * 2048 + (mb & 2047);
          *(uint2*)((u16*)C0 + idx) = *(uint2*)pk;
        } else {
          u16* Cb = (u16*)C0 + (size_t)bz * cB;
          float* Cf = (float*)C0 + (size_t)bz * cB;
          u16* Cl = (OM == 1) ? ((u16*)C1 + (size_t)bz * cB) : (u16*)nullptr;
#pragma unroll
          for (int ri = 0; ri < 4; ri++) {
            const float v = acc[i][j][rq * 4 + ri] * scale + bvs;
            const size_t idx = (size_t)(mb + ri) * ldc + col;
            if (OM == 0) {
              Cb[idx] = f2bf(v);
            } else if (OM == 1) {
              const u16 h = f2bf(v);
              Cb[idx] = h;
              Cl[idx] = f2bf(v - bf2f(h));
            } else {
              Cf[idx] = v;
            }
          }
        }
      }
    }
  }
}

// ---------- row softmax over 2048 fp32 scores, in place + bf16 copy ------------
__global__ __launch_bounds__(256)
void softmax_rows(float* __restrict__ S, u16* __restrict__ Pb) {
  const int row = blockIdx.x;
  float* s = S + (size_t)row * 2048;
  const int tid = threadIdx.x;
  const int w = tid >> 6;
  __shared__ float redm[4];
  __shared__ float reds[4];

  float v[8];
  float mx = -1e30f;
#pragma unroll
  for (int i = 0; i < 8; i++) {
    v[i] = s[tid + 256 * i];
    mx = fmaxf(mx, v[i]);
  }
#pragma unroll
  for (int o = 32; o > 0; o >>= 1) mx = fmaxf(mx, __shfl_xor(mx, o, 64));
  if ((tid & 63) == 0) redm[w] = mx;
  __syncthreads();
  mx = fmaxf(fmaxf(redm[0], redm[1]), fmaxf(redm[2], redm[3]));

  float sum = 0.f;
#pragma unroll
  for (int i = 0; i < 8; i++) {
    v[i] = __expf(v[i] - mx);
    sum += v[i];
  }
#pragma unroll
  for (int o = 32; o > 0; o >>= 1) sum += __shfl_xor(sum, o, 64);
  if ((tid & 63) == 0) reds[w] = sum;
  __syncthreads();
  sum = reds[0] + reds[1] + reds[2] + reds[3];
  const float rs = 1.0f / sum;
#pragma unroll
  for (int i = 0; i < 8; i++) {
    const float p = v[i] * rs;
    s[tid + 256 * i] = p;                              // fp32 p -> d_out (in place)
    Pb[(size_t)row * 2048 + tid + 256 * i] = f2bf(p);  // bf16 p for context GEMM
  }
}

// ---------- launch ------------------------------------------------------------
extern "C" void kernel_launch(void* const* d_in, const int* in_sizes, int n_in,
                              void* d_out, int out_size, void* d_ws, size_t ws_size,
                              hipStream_t stream) {
  const float* x  = (const float*)d_in[0];
  const float* wq = (const float*)d_in[1];
  const float* bq = (const float*)d_in[2];
  const float* wk = (const float*)d_in[3];
  const float* bk = (const float*)d_in[4];
  const float* wv = (const float*)d_in[5];
  const float* bv = (const float*)d_in[6];
  const float* wp = (const float*)d_in[7];
  const float* bp = (const float*)d_in[8];

  const size_t MB = 1024 * 1024;
  char* ws = (char*)d_ws;
  u16* qkvThi = (u16*)(ws + 0 * MB);         // [3072][1024] bf16, 6 MB
  u16* qkvTlo = (u16*)(ws + 6 * MB);         // [2048][1024] bf16, 4 MB
  u16* wpThi  = (u16*)(ws + 10 * MB);        // 2 MB
  u16* xhi    = (u16*)(ws + 13 * MB);        // 16 MB each (8192x1024 bf16)
  u16* xlo    = (u16*)(ws + 29 * MB);
  u16* qhi    = (u16*)(ws + 45 * MB);
  u16* qlo    = (u16*)(ws + 61 * MB);
  u16* khi    = (u16*)(ws + 77 * MB);
  u16* klo    = (u16*)(ws + 93 * MB);
  u16* vT     = (u16*)(ws + 109 * MB);       // [b][1024][2048] bf16, 16 MB
  u16* pbf    = khi;                         // overlay: k dead after scores, 32 MB
  u16* ctx    = qhi;                         // overlay: q dead after scores, 16 MB
  // total ws footprint: 125 MB

  float* outp = (float*)d_out;               // [4,2048,1024] fp32
  float* scf  = (float*)d_out + 8388608;     // scores -> softmax in place -> p fp32

  const dim3 blk(256);

  prep_weights<<<dim3(32, 32, 4), blk, 0, stream>>>(
      wq, wk, wv, wp, qkvThi, qkvTlo, wpThi);
  split_f32<<<dim3(8192), blk, 0, stream>>>(x, xhi, xlo);

  // Q projection: 3-term split, split-plane out. 512 blocks, zero tail.
  gemm_mfma<32, 1, 1, 1, 1><<<dim3(8, 64, 1), blk, 0, stream>>>(
      xhi, xlo, qkvThi, qkvTlo, bq, qhi, qlo,
      1024, 1024, 1024, 1024, 1024, 0, 0, 0, 1.0f);
  // K projection
  gemm_mfma<32, 1, 1, 1, 1><<<dim3(8, 64, 1), blk, 0, stream>>>(
      xhi, xlo, qkvThi + 1024 * 1024, qkvTlo + 1024 * 1024, bk, khi, klo,
      1024, 1024, 1024, 1024, 1024, 0, 0, 0, 1.0f);
  // V projection (hi-only), transposed store vT[b][d][t]
  gemm_mfma<32, 0, 0, 3, 1><<<dim3(8, 64, 1), blk, 0, stream>>>(
      xhi, nullptr, qkvThi + 2 * 1024 * 1024, nullptr, bv, vT, nullptr,
      1024, 1024, 1024, 1024, 0, 0, 0, 0, 1.0f);

  // scores = (q . k) * 32, 3-term split, fp32 into d_out's p region
  gemm_mfma<32, 1, 1, 2, 0><<<dim3(16, 16, 4), blk, 0, stream>>>(
      qhi, qlo, khi, klo, nullptr, scf, nullptr,
      2048, 1024, 1024, 1024, 2048,
      2048LL * 1024, 2048LL * 1024, 2048LL * 2048, 32.0f);

  // softmax rows: fp32 p in place (d_out) + bf16 p for context
  softmax_rows<<<dim3(8192), blk, 0, stream>>>(scf, pbf);

  // context = p @ v (bf16 out), B = vT[d][t] per batch; KB=64
  gemm_mfma<64, 0, 0, 0, 0><<<dim3(8, 16, 4), blk, 0, stream>>>(
      pbf, nullptr, vT, nullptr, nullptr, ctx, nullptr,
      1024, 2048, 2048, 2048, 1024,
      2048LL * 2048, 1024LL * 2048, 2048LL * 1024, 1.0f);

  // output = context @ wp + bp, fp32 out; KB=64
  gemm_mfma<64, 0, 0, 2, 1><<<dim3(8, 64, 1), blk, 0, stream>>>(
      ctx, nullptr, wpThi, nullptr, bp, outp, nullptr,
      1024, 1024, 1024, 1024, 1024, 0, 0, 0, 1.0f);
}

// Round 7
// 501.220 us; speedup vs baseline: 1.0464x; 1.0464x over previous
//
#include <hip/hip_runtime.h>

typedef unsigned short u16;
typedef short bf16x8 __attribute__((ext_vector_type(8)));
typedef float floatx4 __attribute__((ext_vector_type(4)));

// ---------- bf16 helpers (bit-level RNE) --------------------------------------
static __device__ __forceinline__ u16 f2bf(float f) {
  unsigned int u = __float_as_uint(f);
  unsigned int lsb = (u >> 16) & 1u;
  u += 0x7FFFu + lsb;                 // round-to-nearest-even
  return (u16)(u >> 16);
}
static __device__ __forceinline__ float bf2f(u16 u) {
  return __uint_as_float(((unsigned int)u) << 16);
}

// ---------- async global->LDS, 16B per lane (dest = uniform base + lane*16) ----
static __device__ __forceinline__ void gl_lds16(const u16* g, u16* l) {
  __builtin_amdgcn_global_load_lds(
      (const __attribute__((address_space(1))) void*)g,
      (__attribute__((address_space(3))) void*)l, 16, 0, 0);
}

// ---------- weight prep: 4 transposes + qk bias concat in one launch -----------
// z=0: wq -> rows 0..1023 of qkvThi/qkvTlo; z=1: wk -> rows 1024..2047;
// z=2: wv -> rows 2048..3071 of qkvThi (hi only); z=3: wp -> wpThi (hi only);
// z=4 (x<8, y==0): bqk[2048] = bq|bk
__global__ __launch_bounds__(256)
void prep_weights(const float* __restrict__ wq, const float* __restrict__ wk,
                  const float* __restrict__ wv, const float* __restrict__ wp,
                  const float* __restrict__ bq, const float* __restrict__ bk,
                  u16* __restrict__ qkvThi, u16* __restrict__ qkvTlo,
                  u16* __restrict__ wpThi, float* __restrict__ bqk) {
  __shared__ float t[32][33];
  const int z = blockIdx.z;
  const int tid = threadIdx.x;
  if (z == 4) {
    if (blockIdx.y == 0 && blockIdx.x < 8) {
      const int i = blockIdx.x * 256 + tid;
      bqk[i] = (i < 1024) ? bq[i] : bk[i - 1024];
    }
    return;
  }
  const float* in = (z == 0) ? wq : (z == 1) ? wk : (z == 2) ? wv : wp;
  u16* hi = (z == 3) ? wpThi : (qkvThi + (size_t)z * 1024 * 1024);
  u16* lo = (z == 0) ? qkvTlo : (z == 1) ? (qkvTlo + 1024 * 1024) : (u16*)nullptr;
  const int want_lo = (z < 2);

  const int r0 = blockIdx.y * 32, c0 = blockIdx.x * 32;
  const int lr = tid >> 3;            // 0..31
  const int lc = (tid & 7) * 4;       // 0,4,..,28
  float4 v = *(const float4*)(in + (size_t)(r0 + lr) * 1024 + c0 + lc);
  t[lr][lc + 0] = v.x; t[lr][lc + 1] = v.y; t[lr][lc + 2] = v.z; t[lr][lc + 3] = v.w;
  __syncthreads();
  u16 ph[4], pl[4];
#pragma unroll
  for (int j = 0; j < 4; j++) {
    float f = t[lc + j][lr];
    ph[j] = f2bf(f);
    pl[j] = f2bf(f - bf2f(ph[j]));
  }
  const size_t o = (size_t)(c0 + lr) * 1024 + r0 + lc;
  *(uint2*)(hi + o) = *(uint2*)ph;
  if (want_lo) *(uint2*)(lo + o) = *(uint2*)pl;
}

// ---------- fp32 [n] -> split-bf16 hi/lo (elementwise) -------------------------
__global__ __launch_bounds__(256)
void split_f32(const float* __restrict__ in, u16* __restrict__ hi,
               u16* __restrict__ lo) {
  const size_t i4 = ((size_t)blockIdx.x * 256 + threadIdx.x) * 4;
  float4 v = *(const float4*)(in + i4);
  float f[4] = {v.x, v.y, v.z, v.w};
  u16 ph[4], pl[4];
#pragma unroll
  for (int j = 0; j < 4; j++) {
    ph[j] = f2bf(f[j]);
    pl[j] = f2bf(f[j] - bf2f(ph[j]));
  }
  *(uint2*)(hi + i4) = *(uint2*)ph;
  *(uint2*)(lo + i4) = *(uint2*)pl;
}

// ---------- MFMA GEMM, m97 structure: C[M,N] = A[M,K] * B^T (B stored [N][K]) --
// 128x128 tile / 256 threads (4 waves, each 64x64 = 4x4 frags of 16x16x32 bf16
// — the measured-conflict-free, 881 TF plateau config; 32x32 swap measured WORSE).
// KB = K-tile (32/64). Staging: global_load_lds 16B/lane into XOR-swizzled LDS
// (KB32: logical col-blk c of row r at phys c^((r>>1)&3); KB64: c^(r&7)) —
// DMA-legal AND measured 0 bank conflicts for the 16x16 frag b128 reads.
// ASP/BSP: hi/lo bf16 planes -> 3-term split product (hh + hl + lh).
// OM: 0 bf16 out, 1 split bf16 (hi->C0, lo->C1), 2 fp32 out,
//     3 bf16 transposed V-store vT[b][d][t], b=m>>11, t=m&2047 (2048x1024 hard),
//     5 QK-routed planar split: col<1024 -> C0/C1, else C2/C3 (ldc=1024 each).
template<int KB, int ASP, int BSP, int OM, int HB>
__global__ __launch_bounds__(256)
void gemm_mfma(const u16* __restrict__ Ahi, const u16* __restrict__ Alo,
               const u16* __restrict__ Bhi, const u16* __restrict__ Blo,
               const float* __restrict__ bias,
               void* __restrict__ C0, void* __restrict__ C1,
               void* __restrict__ C2, void* __restrict__ C3,
               int N, int K, int lda, int ldb, int ldc,
               long long aB, long long bB, long long cB, float scale) {
  constexpr int CM = KB / 8 - 1;      // col-block mask (3 or 7)
  constexpr int RPI = 512 / KB;       // rows per 1KB DMA issue (16 or 8)
  constexpr int NI = KB / 16;         // issues per wave per plane (2 or 4)
  constexpr int PL = 128 * KB;        // plane elems
  __shared__ __align__(16) u16 As[(1 + ASP) * PL];
  __shared__ __align__(16) u16 Bs[(1 + BSP) * PL];

  const int bz = blockIdx.z;
  const u16* A0 = Ahi + (size_t)bz * aB;
  const u16* A1 = ASP ? (Alo + (size_t)bz * aB) : (const u16*)nullptr;
  const u16* B0 = Bhi + (size_t)bz * bB;
  const u16* B1 = BSP ? (Blo + (size_t)bz * bB) : (const u16*)nullptr;

  const int m0 = blockIdx.y * 128;
  const int n0 = blockIdx.x * 128;
  const int tid = threadIdx.x;
  const int w = tid >> 6;
  const int L = tid & 63;
  const int rr = L & 15, quad = L >> 4;
  const int wm = (w >> 1) * 64, wn = (w & 1) * 64;

  // staging: wave w stages rows [w*32, w*32+32) of each 128xKB plane.
  const int lrow = (KB == 32) ? (L >> 2) : (L >> 3);
  const int c3 = (L & CM) ^ ((L >> 3) & CM);    // logical (global) col-block
  const int srow = w * 32 + lrow;
  u16* stA = &As[w * 32 * KB];
  u16* stB = &Bs[w * 32 * KB];
  const u16* gA0 = A0 + (size_t)(m0 + srow) * lda + c3 * 8;
  const u16* gA1 = ASP ? A1 + (size_t)(m0 + srow) * lda + c3 * 8 : (const u16*)nullptr;
  const u16* gB0 = B0 + (size_t)(n0 + srow) * ldb + c3 * 8;
  const u16* gB1 = BSP ? B1 + (size_t)(n0 + srow) * ldb + c3 * 8 : (const u16*)nullptr;

  floatx4 acc[4][4] = {};

  for (int k0 = 0; k0 < K; k0 += KB) {
#pragma unroll
    for (int q = 0; q < NI; q++) {
      gl_lds16(gA0 + k0 + (size_t)q * RPI * lda, stA + q * 512);
      gl_lds16(gB0 + k0 + (size_t)q * RPI * ldb, stB + q * 512);
    }
    if (ASP) {
#pragma unroll
      for (int q = 0; q < NI; q++)
        gl_lds16(gA1 + k0 + (size_t)q * RPI * lda, stA + PL + q * 512);
    }
    if (BSP) {
#pragma unroll
      for (int q = 0; q < NI; q++)
        gl_lds16(gB1 + k0 + (size_t)q * RPI * ldb, stB + PL + q * 512);
    }
    __syncthreads();                  // drains vmcnt(0) then barrier

#pragma unroll
    for (int s = 0; s < KB / 32; s++) {
      // frag phys col-block for logical k-chunk s (lane-constant)
      const int pcb = ((KB == 32) ? (quad ^ ((rr >> 1) & 3))
                                  : ((s * 4 + quad) ^ (rr & 7))) * 8;
      bf16x8 a0[4], a1[4], b0[4], b1[4];
#pragma unroll
      for (int i = 0; i < 4; i++) {
        const int arow = wm + i * 16 + rr;
        const int brow = wn + i * 16 + rr;
        a0[i] = *(const bf16x8*)&As[arow * KB + pcb];
        b0[i] = *(const bf16x8*)&Bs[brow * KB + pcb];
        if (ASP) a1[i] = *(const bf16x8*)&As[PL + arow * KB + pcb];
        if (BSP) b1[i] = *(const bf16x8*)&Bs[PL + brow * KB + pcb];
      }
#pragma unroll
      for (int i = 0; i < 4; i++) {
#pragma unroll
        for (int j = 0; j < 4; j++) {
          acc[i][j] = __builtin_amdgcn_mfma_f32_16x16x32_bf16(a0[i], b0[j], acc[i][j], 0, 0, 0);
          if (ASP && BSP) {
            acc[i][j] = __builtin_amdgcn_mfma_f32_16x16x32_bf16(a0[i], b1[j], acc[i][j], 0, 0, 0);
            acc[i][j] = __builtin_amdgcn_mfma_f32_16x16x32_bf16(a1[i], b0[j], acc[i][j], 0, 0, 0);
          }
        }
      }
    }
    __syncthreads();                  // frag reads done before next DMA stage
  }

  // epilogue: D[m = quad*4+ii][n = rr] per 16x16 fragment (m89-verified)
#pragma unroll
  for (int i = 0; i < 4; i++) {
    const int mbase = m0 + wm + i * 16 + quad * 4;
#pragma unroll
    for (int j = 0; j < 4; j++) {
      const int col = n0 + wn + j * 16 + rr;
      float bvs = 0.f;
      if (HB) bvs = bias[col];
      if (OM == 3) {
        u16 pk[4];
#pragma unroll
        for (int ii = 0; ii < 4; ii++) pk[ii] = f2bf(acc[i][j][ii] * scale + bvs);
        const size_t idx = (size_t)(mbase >> 11) * (2048 * 1024) +
                           (size_t)col * 2048 + (mbase & 2047);
        *(uint2*)((u16*)C0 + idx) = *(uint2*)pk;
      } else if (OM == 5) {
        u16* hi; u16* lo;
        if (col < 1024) { hi = (u16*)C0; lo = (u16*)C1; }
        else            { hi = (u16*)C2; lo = (u16*)C3; }
        const int cc = col & 1023;
#pragma unroll
        for (int ii = 0; ii < 4; ii++) {
          const float v = acc[i][j][ii] + bvs;
          const size_t idx = (size_t)(mbase + ii) * 1024 + cc;
          const u16 h = f2bf(v);
          hi[idx] = h;
          lo[idx] = f2bf(v - bf2f(h));
        }
      } else {
        u16* Cb = (u16*)C0 + (size_t)bz * cB;
        float* Cf = (float*)C0 + (size_t)bz * cB;
        u16* Cl = (OM == 1) ? ((u16*)C1 + (size_t)bz * cB) : (u16*)nullptr;
#pragma unroll
        for (int ii = 0; ii < 4; ii++) {
          const float v = acc[i][j][ii] * scale + bvs;
          const size_t idx = (size_t)(mbase + ii) * ldc + col;
          if (OM == 0) {
            Cb[idx] = f2bf(v);
          } else if (OM == 1) {
            const u16 h = f2bf(v);
            Cb[idx] = h;
            Cl[idx] = f2bf(v - bf2f(h));
          } else {
            Cf[idx] = v;
          }
        }
      }
    }
  }
}

// ---------- row softmax over 2048 fp32 scores, in place + bf16 copy ------------
__global__ __launch_bounds__(256)
void softmax_rows(float* __restrict__ S, u16* __restrict__ Pb) {
  const int row = blockIdx.x;
  float* s = S + (size_t)row * 2048;
  const int tid = threadIdx.x;
  const int w = tid >> 6;
  __shared__ float redm[4];
  __shared__ float reds[4];

  float v[8];
  float mx = -1e30f;
#pragma unroll
  for (int i = 0; i < 8; i++) {
    v[i] = s[tid + 256 * i];
    mx = fmaxf(mx, v[i]);
  }
#pragma unroll
  for (int o = 32; o > 0; o >>= 1) mx = fmaxf(mx, __shfl_xor(mx, o, 64));
  if ((tid & 63) == 0) redm[w] = mx;
  __syncthreads();
  mx = fmaxf(fmaxf(redm[0], redm[1]), fmaxf(redm[2], redm[3]));

  float sum = 0.f;
#pragma unroll
  for (int i = 0; i < 8; i++) {
    v[i] = __expf(v[i] - mx);
    sum += v[i];
  }
#pragma unroll
  for (int o = 32; o > 0; o >>= 1) sum += __shfl_xor(sum, o, 64);
  if ((tid & 63) == 0) reds[w] = sum;
  __syncthreads();
  sum = reds[0] + reds[1] + reds[2] + reds[3];
  const float rs = 1.0f / sum;
#pragma unroll
  for (int i = 0; i < 8; i++) {
    const float p = v[i] * rs;
    s[tid + 256 * i] = p;                              // fp32 p -> d_out (in place)
    Pb[(size_t)row * 2048 + tid + 256 * i] = f2bf(p);  // bf16 p for context GEMM
  }
}

// ---------- launch ------------------------------------------------------------
extern "C" void kernel_launch(void* const* d_in, const int* in_sizes, int n_in,
                              void* d_out, int out_size, void* d_ws, size_t ws_size,
                              hipStream_t stream) {
  const float* x  = (const float*)d_in[0];
  const float* wq = (const float*)d_in[1];
  const float* bq = (const float*)d_in[2];
  const float* wk = (const float*)d_in[3];
  const float* bk = (const float*)d_in[4];
  const float* wv = (const float*)d_in[5];
  const float* bv = (const float*)d_in[6];
  const float* wp = (const float*)d_in[7];
  const float* bp = (const float*)d_in[8];

  const size_t MB = 1024 * 1024;
  char* ws = (char*)d_ws;
  u16* qkvThi = (u16*)(ws + 0 * MB);         // [3072][1024] bf16, 6 MB
  u16* qkvTlo = (u16*)(ws + 6 * MB);         // [2048][1024] bf16, 4 MB
  u16* wpThi  = (u16*)(ws + 10 * MB);        // 2 MB
  float* bqk  = (float*)(ws + 12 * MB);      // 8 KB
  u16* xhi    = (u16*)(ws + 13 * MB);        // 16 MB each (8192x1024 bf16)
  u16* xlo    = (u16*)(ws + 29 * MB);
  u16* qhi    = (u16*)(ws + 45 * MB);
  u16* qlo    = (u16*)(ws + 61 * MB);
  u16* khi    = (u16*)(ws + 77 * MB);
  u16* klo    = (u16*)(ws + 93 * MB);
  u16* vT     = (u16*)(ws + 109 * MB);       // [b][1024][2048] bf16, 16 MB
  u16* pbf    = khi;                         // overlay: k dead after scores, 32 MB
  u16* ctx    = qhi;                         // overlay: q dead after scores, 16 MB
  // total ws footprint: 125 MB

  float* outp = (float*)d_out;               // [4,2048,1024] fp32
  float* scf  = (float*)d_out + 8388608;     // scores -> softmax in place -> p fp32

  const dim3 blk(256);

  prep_weights<<<dim3(32, 32, 5), blk, 0, stream>>>(
      wq, wk, wv, wp, bq, bk, qkvThi, qkvTlo, wpThi, bqk);
  split_f32<<<dim3(8192), blk, 0, stream>>>(x, xhi, xlo);

  // fused Q|K projection: N=2048 uniform 3-term split tiles, planar routed
  // split outputs. 1024 blocks = exactly 2x512 co-resident rounds, zero tail.
  gemm_mfma<32, 1, 1, 5, 1><<<dim3(16, 64, 1), blk, 0, stream>>>(
      xhi, xlo, qkvThi, qkvTlo, bqk, qhi, qlo, khi, klo,
      2048, 1024, 1024, 1024, 1024, 0, 0, 0, 1.0f);

  // V projection (hi-only), transposed store vT[b][d][t]
  gemm_mfma<32, 0, 0, 3, 1><<<dim3(8, 64, 1), blk, 0, stream>>>(
      xhi, nullptr, qkvThi + 2 * 1024 * 1024, nullptr, bv, vT, nullptr, nullptr, nullptr,
      1024, 1024, 1024, 1024, 0, 0, 0, 0, 1.0f);

  // scores = (q . k) * 32, 3-term split, fp32 into d_out's p region
  gemm_mfma<32, 1, 1, 2, 0><<<dim3(16, 16, 4), blk, 0, stream>>>(
      qhi, qlo, khi, klo, nullptr, scf, nullptr, nullptr, nullptr,
      2048, 1024, 1024, 1024, 2048,
      2048LL * 1024, 2048LL * 1024, 2048LL * 2048, 32.0f);

  // softmax rows: fp32 p in place (d_out) + bf16 p for context
  softmax_rows<<<dim3(8192), blk, 0, stream>>>(scf, pbf);

  // context = p @ v (bf16 out), B = vT[d][t] per batch; KB=64
  gemm_mfma<64, 0, 0, 0, 0><<<dim3(8, 16, 4), blk, 0, stream>>>(
      pbf, nullptr, vT, nullptr, nullptr, ctx, nullptr, nullptr, nullptr,
      1024, 2048, 2048, 2048, 1024,
      2048LL * 2048, 1024LL * 2048, 2048LL * 1024, 1.0f);

  // output = context @ wp + bp, fp32 out; KB=64
  gemm_mfma<64, 0, 0, 2, 1><<<dim3(8, 64, 1), blk, 0, stream>>>(
      ctx, nullptr, wpThi, nullptr, bp, outp, nullptr, nullptr, nullptr,
      1024, 1024, 1024, 1024, 1024, 0, 0, 0, 1.0f);
}

// Round 8
// 476.612 us; speedup vs baseline: 1.1004x; 1.0516x over previous
//
#include <hip/hip_runtime.h>

typedef unsigned short u16;
typedef short bf16x8 __attribute__((ext_vector_type(8)));
typedef float floatx4 __attribute__((ext_vector_type(4)));

// ---------- bf16 helpers (bit-level RNE) --------------------------------------
static __device__ __forceinline__ u16 f2bf(float f) {
  unsigned int u = __float_as_uint(f);
  unsigned int lsb = (u >> 16) & 1u;
  u += 0x7FFFu + lsb;                 // round-to-nearest-even
  return (u16)(u >> 16);
}
static __device__ __forceinline__ float bf2f(u16 u) {
  return __uint_as_float(((unsigned int)u) << 16);
}

// ---------- async global->LDS, 16B per lane (dest = uniform base + lane*16) ----
static __device__ __forceinline__ void gl_lds16(const u16* g, u16* l) {
  __builtin_amdgcn_global_load_lds(
      (const __attribute__((address_space(1))) void*)g,
      (__attribute__((address_space(3))) void*)l, 16, 0, 0);
}

// ---------- unified prep: weight transposes + bias concat + x split/transpose --
// z=0: wq -> rows 0..1023 of qkThi/qkTlo (split, transposed)
// z=1: wk -> rows 1024..2047 of qkThi/qkTlo
// z=2: wv -> wvThi (hi only, transposed)
// z=3: wp -> wpThi (hi only, transposed)
// z=4 (x<8, y==0): bqk[2048] = bq|bk
// z=5..12: x fp32 [8192][1024] -> xhi/xlo planar + xThi[b][1024][2048] (hi)
__global__ __launch_bounds__(256)
void prep_all(const float* __restrict__ wq, const float* __restrict__ wk,
              const float* __restrict__ wv, const float* __restrict__ wp,
              const float* __restrict__ bq, const float* __restrict__ bk,
              const float* __restrict__ x,
              u16* __restrict__ qkThi, u16* __restrict__ qkTlo,
              u16* __restrict__ wvThi, u16* __restrict__ wpThi,
              float* __restrict__ bqk,
              u16* __restrict__ xhi, u16* __restrict__ xlo,
              u16* __restrict__ xThi) {
  __shared__ float t[32][33];
  const int z = blockIdx.z;
  const int tid = threadIdx.x;
  const int lr = tid >> 3;            // 0..31
  const int lc = (tid & 7) * 4;       // 0,4,..,28

  if (z == 4) {
    if (blockIdx.y == 0 && blockIdx.x < 8) {
      const int i = blockIdx.x * 256 + tid;
      bqk[i] = (i < 1024) ? bq[i] : bk[i - 1024];
    }
    return;
  }

  if (z >= 5) {
    // x slab: tile-row index (z-5)*32 + by, cols bx*32
    const int r0 = ((z - 5) * 32 + blockIdx.y) * 32;
    const int c0 = blockIdx.x * 32;
    float4 v = *(const float4*)(x + (size_t)(r0 + lr) * 1024 + c0 + lc);
    float f[4] = {v.x, v.y, v.z, v.w};
    t[lr][lc + 0] = v.x; t[lr][lc + 1] = v.y; t[lr][lc + 2] = v.z; t[lr][lc + 3] = v.w;
    u16 ph[4], pl[4];
#pragma unroll
    for (int j = 0; j < 4; j++) {
      ph[j] = f2bf(f[j]);
      pl[j] = f2bf(f[j] - bf2f(ph[j]));
    }
    const size_t o = (size_t)(r0 + lr) * 1024 + c0 + lc;
    *(uint2*)(xhi + o) = *(uint2*)ph;
    *(uint2*)(xlo + o) = *(uint2*)pl;
    __syncthreads();
    u16 pt[4];
#pragma unroll
    for (int j = 0; j < 4; j++) pt[j] = f2bf(t[lc + j][lr]);
    const int b = r0 >> 11, rt = r0 & 2047;
    *(uint2*)(xThi + (size_t)b * (1024 * 2048) + (size_t)(c0 + lr) * 2048 + rt + lc) =
        *(uint2*)pt;
    return;
  }

  // weight transposes (z 0..3)
  const float* in = (z == 0) ? wq : (z == 1) ? wk : (z == 2) ? wv : wp;
  u16* hi = (z == 2) ? wvThi : (z == 3) ? wpThi : (qkThi + (size_t)z * 1024 * 1024);
  u16* lo = (z == 0) ? qkTlo : (z == 1) ? (qkTlo + 1024 * 1024) : (u16*)nullptr;
  const int want_lo = (z < 2);

  const int r0 = blockIdx.y * 32, c0 = blockIdx.x * 32;
  float4 v = *(const float4*)(in + (size_t)(r0 + lr) * 1024 + c0 + lc);
  t[lr][lc + 0] = v.x; t[lr][lc + 1] = v.y; t[lr][lc + 2] = v.z; t[lr][lc + 3] = v.w;
  __syncthreads();
  u16 ph[4], pl[4];
#pragma unroll
  for (int j = 0; j < 4; j++) {
    float f = t[lc + j][lr];
    ph[j] = f2bf(f);
    if (want_lo) pl[j] = f2bf(f - bf2f(ph[j]));
  }
  const size_t o = (size_t)(c0 + lr) * 1024 + r0 + lc;
  *(uint2*)(hi + o) = *(uint2*)ph;
  if (want_lo) *(uint2*)(lo + o) = *(uint2*)pl;
}

// ---------- MFMA GEMM, m97 structure: C[M,N] = A[M,K] * B^T (B stored [N][K]) --
// 128x128 tile / 256 threads (4 waves, each 64x64 = 4x4 frags of 16x16x32 bf16
// — measured-conflict-free 881 TF plateau config; 32x32 core measured WORSE).
// KB = K-tile (32/64). Staging: global_load_lds 16B/lane into XOR-swizzled LDS
// (KB32: logical col-blk c of row r at phys c^((r>>1)&3); KB64: c^(r&7)).
// ASP/BSP: hi/lo bf16 planes -> 3-term split product (hh + hl + lh).
// OM: 0 bf16 out, 1 split bf16 (hi->C0, lo->C1), 2 fp32 out,
//     5 QK-routed planar split: col<1024 -> C0/C1, else C2/C3 (ldc=1024 each).
template<int KB, int ASP, int BSP, int OM, int HB>
__global__ __launch_bounds__(256)
void gemm_mfma(const u16* __restrict__ Ahi, const u16* __restrict__ Alo,
               const u16* __restrict__ Bhi, const u16* __restrict__ Blo,
               const float* __restrict__ bias,
               void* __restrict__ C0, void* __restrict__ C1,
               void* __restrict__ C2, void* __restrict__ C3,
               int N, int K, int lda, int ldb, int ldc,
               long long aB, long long bB, long long cB, float scale) {
  constexpr int CM = KB / 8 - 1;      // col-block mask (3 or 7)
  constexpr int RPI = 512 / KB;       // rows per 1KB DMA issue (16 or 8)
  constexpr int NI = KB / 16;         // issues per wave per plane (2 or 4)
  constexpr int PL = 128 * KB;        // plane elems
  __shared__ __align__(16) u16 As[(1 + ASP) * PL];
  __shared__ __align__(16) u16 Bs[(1 + BSP) * PL];

  const int bz = blockIdx.z;
  const u16* A0 = Ahi + (size_t)bz * aB;
  const u16* A1 = ASP ? (Alo + (size_t)bz * aB) : (const u16*)nullptr;
  const u16* B0 = Bhi + (size_t)bz * bB;
  const u16* B1 = BSP ? (Blo + (size_t)bz * bB) : (const u16*)nullptr;

  const int m0 = blockIdx.y * 128;
  const int n0 = blockIdx.x * 128;
  const int tid = threadIdx.x;
  const int w = tid >> 6;
  const int L = tid & 63;
  const int rr = L & 15, quad = L >> 4;
  const int wm = (w >> 1) * 64, wn = (w & 1) * 64;

  // staging: wave w stages rows [w*32, w*32+32) of each 128xKB plane.
  const int lrow = (KB == 32) ? (L >> 2) : (L >> 3);
  const int c3 = (L & CM) ^ ((L >> 3) & CM);    // logical (global) col-block
  const int srow = w * 32 + lrow;
  u16* stA = &As[w * 32 * KB];
  u16* stB = &Bs[w * 32 * KB];
  const u16* gA0 = A0 + (size_t)(m0 + srow) * lda + c3 * 8;
  const u16* gA1 = ASP ? A1 + (size_t)(m0 + srow) * lda + c3 * 8 : (const u16*)nullptr;
  const u16* gB0 = B0 + (size_t)(n0 + srow) * ldb + c3 * 8;
  const u16* gB1 = BSP ? B1 + (size_t)(n0 + srow) * ldb + c3 * 8 : (const u16*)nullptr;

  floatx4 acc[4][4] = {};

  for (int k0 = 0; k0 < K; k0 += KB) {
#pragma unroll
    for (int q = 0; q < NI; q++) {
      gl_lds16(gA0 + k0 + (size_t)q * RPI * lda, stA + q * 512);
      gl_lds16(gB0 + k0 + (size_t)q * RPI * ldb, stB + q * 512);
    }
    if (ASP) {
#pragma unroll
      for (int q = 0; q < NI; q++)
        gl_lds16(gA1 + k0 + (size_t)q * RPI * lda, stA + PL + q * 512);
    }
    if (BSP) {
#pragma unroll
      for (int q = 0; q < NI; q++)
        gl_lds16(gB1 + k0 + (size_t)q * RPI * ldb, stB + PL + q * 512);
    }
    __syncthreads();                  // drains vmcnt(0) then barrier

#pragma unroll
    for (int s = 0; s < KB / 32; s++) {
      // frag phys col-block for logical k-chunk s (lane-constant)
      const int pcb = ((KB == 32) ? (quad ^ ((rr >> 1) & 3))
                                  : ((s * 4 + quad) ^ (rr & 7))) * 8;
      bf16x8 a0[4], a1[4], b0[4], b1[4];
#pragma unroll
      for (int i = 0; i < 4; i++) {
        const int arow = wm + i * 16 + rr;
        const int brow = wn + i * 16 + rr;
        a0[i] = *(const bf16x8*)&As[arow * KB + pcb];
        b0[i] = *(const bf16x8*)&Bs[brow * KB + pcb];
        if (ASP) a1[i] = *(const bf16x8*)&As[PL + arow * KB + pcb];
        if (BSP) b1[i] = *(const bf16x8*)&Bs[PL + brow * KB + pcb];
      }
#pragma unroll
      for (int i = 0; i < 4; i++) {
#pragma unroll
        for (int j = 0; j < 4; j++) {
          acc[i][j] = __builtin_amdgcn_mfma_f32_16x16x32_bf16(a0[i], b0[j], acc[i][j], 0, 0, 0);
          if (ASP && BSP) {
            acc[i][j] = __builtin_amdgcn_mfma_f32_16x16x32_bf16(a0[i], b1[j], acc[i][j], 0, 0, 0);
            acc[i][j] = __builtin_amdgcn_mfma_f32_16x16x32_bf16(a1[i], b0[j], acc[i][j], 0, 0, 0);
          }
        }
      }
    }
    __syncthreads();                  // frag reads done before next DMA stage
  }

  // epilogue: D[m = quad*4+ii][n = rr] per 16x16 fragment (m89-verified)
#pragma unroll
  for (int i = 0; i < 4; i++) {
    const int mbase = m0 + wm + i * 16 + quad * 4;
#pragma unroll
    for (int j = 0; j < 4; j++) {
      const int col = n0 + wn + j * 16 + rr;
      float bvs = 0.f;
      if (HB) bvs = bias[col];
      if (OM == 5) {
        u16* hi; u16* lo;
        if (col < 1024) { hi = (u16*)C0; lo = (u16*)C1; }
        else            { hi = (u16*)C2; lo = (u16*)C3; }
        const int cc = col & 1023;
#pragma unroll
        for (int ii = 0; ii < 4; ii++) {
          const float v = acc[i][j][ii] + bvs;
          const size_t idx = (size_t)(mbase + ii) * 1024 + cc;
          const u16 h = f2bf(v);
          hi[idx] = h;
          lo[idx] = f2bf(v - bf2f(h));
        }
      } else {
        u16* Cb = (u16*)C0 + (size_t)bz * cB;
        float* Cf = (float*)C0 + (size_t)bz * cB;
        u16* Cl = (OM == 1) ? ((u16*)C1 + (size_t)bz * cB) : (u16*)nullptr;
#pragma unroll
        for (int ii = 0; ii < 4; ii++) {
          const float v = acc[i][j][ii] * scale + bvs;
          const size_t idx = (size_t)(mbase + ii) * ldc + col;
          if (OM == 0) {
            Cb[idx] = f2bf(v);
          } else if (OM == 1) {
            const u16 h = f2bf(v);
            Cb[idx] = h;
            Cl[idx] = f2bf(v - bf2f(h));
          } else {
            Cf[idx] = v;
          }
        }
      }
    }
  }
}

// ---------- row softmax over 2048 fp32 scores, in place + bf16 copy ------------
__global__ __launch_bounds__(256)
void softmax_rows(float* __restrict__ S, u16* __restrict__ Pb) {
  const int row = blockIdx.x;
  float* s = S + (size_t)row * 2048;
  const int tid = threadIdx.x;
  const int w = tid >> 6;
  __shared__ float redm[4];
  __shared__ float reds[4];

  float v[8];
  float mx = -1e30f;
#pragma unroll
  for (int i = 0; i < 8; i++) {
    v[i] = s[tid + 256 * i];
    mx = fmaxf(mx, v[i]);
  }
#pragma unroll
  for (int o = 32; o > 0; o >>= 1) mx = fmaxf(mx, __shfl_xor(mx, o, 64));
  if ((tid & 63) == 0) redm[w] = mx;
  __syncthreads();
  mx = fmaxf(fmaxf(redm[0], redm[1]), fmaxf(redm[2], redm[3]));

  float sum = 0.f;
#pragma unroll
  for (int i = 0; i < 8; i++) {
    v[i] = __expf(v[i] - mx);
    sum += v[i];
  }
#pragma unroll
  for (int o = 32; o > 0; o >>= 1) sum += __shfl_xor(sum, o, 64);
  if ((tid & 63) == 0) reds[w] = sum;
  __syncthreads();
  sum = reds[0] + reds[1] + reds[2] + reds[3];
  const float rs = 1.0f / sum;
#pragma unroll
  for (int i = 0; i < 8; i++) {
    const float p = v[i] * rs;
    s[tid + 256 * i] = p;                              // fp32 p -> d_out (in place)
    Pb[(size_t)row * 2048 + tid + 256 * i] = f2bf(p);  // bf16 p for px GEMM
  }
}

// ---------- launch ------------------------------------------------------------
extern "C" void kernel_launch(void* const* d_in, const int* in_sizes, int n_in,
                              void* d_out, int out_size, void* d_ws, size_t ws_size,
                              hipStream_t stream) {
  const float* x  = (const float*)d_in[0];
  const float* wq = (const float*)d_in[1];
  const float* bq = (const float*)d_in[2];
  const float* wk = (const float*)d_in[3];
  const float* bk = (const float*)d_in[4];
  const float* wv = (const float*)d_in[5];
  const float* bv = (const float*)d_in[6];
  const float* wp = (const float*)d_in[7];
  const float* bp = (const float*)d_in[8];

  const size_t MB = 1024 * 1024;
  char* ws = (char*)d_ws;
  u16* qkThi = (u16*)(ws + 0 * MB);          // [2048][1024] bf16, 4 MB
  u16* qkTlo = (u16*)(ws + 4 * MB);          // 4 MB
  u16* wvThi = (u16*)(ws + 8 * MB);          // 2 MB
  u16* wpThi = (u16*)(ws + 10 * MB);         // 2 MB
  float* bqk = (float*)(ws + 12 * MB);       // 8 KB
  u16* xhi   = (u16*)(ws + 13 * MB);         // 16 MB each (8192x1024 bf16)
  u16* xlo   = (u16*)(ws + 29 * MB);
  u16* qhi   = (u16*)(ws + 45 * MB);
  u16* qlo   = (u16*)(ws + 61 * MB);
  u16* khi   = (u16*)(ws + 77 * MB);
  u16* klo   = (u16*)(ws + 93 * MB);
  u16* xThi  = (u16*)(ws + 109 * MB);        // [b][1024][2048] bf16, 16 MB
  u16* pbf   = khi;                          // overlay: k dead after scores, 32 MB
  u16* px    = qhi;                          // overlay: q dead after scores, 16 MB
  u16* ctx   = qlo;                          // overlay, 16 MB
  // total ws footprint: 125 MB

  float* outp = (float*)d_out;               // [4,2048,1024] fp32
  float* scf  = (float*)d_out + 8388608;     // scores -> softmax in place -> p fp32

  const dim3 blk(256);

  // prep: weights + bias + x split/transpose, one launch
  prep_all<<<dim3(32, 32, 13), blk, 0, stream>>>(
      wq, wk, wv, wp, bq, bk, x, qkThi, qkTlo, wvThi, wpThi, bqk, xhi, xlo, xThi);

  // fused Q|K projection: N=2048 uniform 3-term split tiles, planar routed
  // split outputs. 1024 blocks.
  gemm_mfma<32, 1, 1, 5, 1><<<dim3(16, 64, 1), blk, 0, stream>>>(
      xhi, xlo, qkThi, qkTlo, bqk, qhi, qlo, khi, klo,
      2048, 1024, 1024, 1024, 1024, 0, 0, 0, 1.0f);

  // scores = (q . k) * 32, 3-term split, fp32 into d_out's p region
  gemm_mfma<32, 1, 1, 2, 0><<<dim3(16, 16, 4), blk, 0, stream>>>(
      qhi, qlo, khi, klo, nullptr, scf, nullptr, nullptr, nullptr,
      2048, 1024, 1024, 1024, 2048,
      2048LL * 1024, 2048LL * 1024, 2048LL * 2048, 32.0f);

  // softmax rows: fp32 p in place (d_out) + bf16 p
  softmax_rows<<<dim3(8192), blk, 0, stream>>>(scf, pbf);

  // px = p @ x   (reassociation: ctx = (p@x)@wv + bv since rows of p sum to 1)
  gemm_mfma<64, 0, 0, 0, 0><<<dim3(8, 16, 4), blk, 0, stream>>>(
      pbf, nullptr, xThi, nullptr, nullptr, px, nullptr, nullptr, nullptr,
      1024, 2048, 2048, 2048, 1024,
      2048LL * 2048, 1024LL * 2048, 2048LL * 1024, 1.0f);

  // ctx = px @ wv + bv (bf16 out)
  gemm_mfma<64, 0, 0, 0, 1><<<dim3(8, 64, 1), blk, 0, stream>>>(
      px, nullptr, wvThi, nullptr, bv, ctx, nullptr, nullptr, nullptr,
      1024, 1024, 1024, 1024, 1024, 0, 0, 0, 1.0f);

  // output = ctx @ wp + bp, fp32 out
  gemm_mfma<64, 0, 0, 2, 1><<<dim3(8, 64, 1), blk, 0, stream>>>(
      ctx, nullptr, wpThi, nullptr, bp, outp, nullptr, nullptr, nullptr,
      1024, 1024, 1024, 1024, 1024, 0, 0, 0, 1.0f);
}